// Round 1
// baseline (184.769 us; speedup 1.0000x reference)
//
#include <hip/hip_runtime.h>
#include <hip/hip_bf16.h>

typedef __bf16 bf16x8 __attribute__((ext_vector_type(8)));
typedef __bf16 bf16x4 __attribute__((ext_vector_type(4)));
typedef float  f32x16 __attribute__((ext_vector_type(16)));
typedef float  f32x4  __attribute__((ext_vector_type(4)));
typedef float  f32x2  __attribute__((ext_vector_type(2)));

static __device__ __forceinline__ f32x16 mfma32(bf16x8 a, bf16x8 b, f32x16 c) {
    return __builtin_amdgcn_mfma_f32_32x32x16_bf16(a, b, c, 0, 0, 0);
}

// gelu-tanh via sigmoid with log2e folded in:
// gelu(h) = h / (1 + exp2(-h*(C1 + C2*h^2)))
#define GELU_C1 2.30220820f
#define GELU_C2 0.10294324f

// ---------------------------------------------------------------------------
// Pack kernel: W1p (K=144, bias folded), W2p (sigma-permuted), plus router
// weights converted to fp64. Unchanged from previous version.
// ---------------------------------------------------------------------------
__global__ __launch_bounds__(256) void pack_kernel(
    const float* __restrict__ We1, const float* __restrict__ be1,
    const float* __restrict__ Ws1, const float* __restrict__ bs1,
    const float* __restrict__ We2, const float* __restrict__ Ws2,
    const float* __restrict__ Wr1, const float* __restrict__ br1,
    const float* __restrict__ Wr2, const float* __restrict__ br2,
    __bf16* __restrict__ w1p, __bf16* __restrict__ w2p,
    double* __restrict__ wr1d, double* __restrict__ br1d,
    double* __restrict__ wr2d, double* __restrict__ br2d)
{
    int tid = blockIdx.x * 256 + threadIdx.x;
    if (tid < 23040) {
        int l  = tid & 63;
        int ks = (tid >> 6) % 9;
        int nt = (tid / 576) & 3;
        int e  = tid / 2304;
        const float* src = (e < 8) ? (We1 + e * 16384) : (Ws1 + (e - 8) * 16384);
        const float* bia = (e < 8) ? (be1 + e * 128)   : (bs1 + (e - 8) * 128);
        int n = nt * 32 + (l & 31);
        int kb = ks * 16 + (l >> 5) * 8;
        bf16x8 v;
        #pragma unroll
        for (int j = 0; j < 8; ++j) {
            int k = kb + j;
            float f = (k < 128) ? src[k * 128 + n] : ((k == 128) ? bia[n] : 0.f);
            v[j] = (__bf16)f;
        }
        *(bf16x8*)(w1p + (size_t)tid * 8) = v;
    } else if (tid < 43520) {
        int t2 = tid - 23040;
        int l  = t2 & 63;
        int ks = (t2 >> 6) & 7;
        int ot = (t2 / 512) & 3;
        int e  = t2 / 2048;
        const float* src = (e < 8) ? (We2 + e * 16384) : (Ws2 + (e - 8) * 16384);
        int o  = ot * 32 + (l & 31);
        int lh = l >> 5;
        bf16x8 v;
        #pragma unroll
        for (int j = 0; j < 8; ++j) {
            int hid = 16 * ks + 8 * (j >> 2) + 4 * lh + (j & 3);
            v[j] = (__bf16)src[hid * 128 + o];
        }
        *(bf16x8*)(w2p + (size_t)t2 * 8) = v;
    } else if (tid < 45568) {
        int i = tid - 43520;            // 0..2047: Wr1 [128][16]
        wr1d[i] = (double)Wr1[i];
    } else if (tid < 45696) {
        int i = tid - 45568;            // 0..127: Wr2 [16][8]
        wr2d[i] = (double)Wr2[i];
    } else if (tid < 45712) {
        int i = tid - 45696;            // 0..15
        br1d[i] = (double)br1[i];
    } else if (tid < 45720) {
        int i = tid - 45712;            // 0..7
        br2d[i] = (double)br2[i];
    }
}

// ---------------------------------------------------------------------------
// Router kernel (fp64, decision-exact): computes masked-softmax gates for all
// tokens. Code is the verbatim router phase of the previous fused kernel, so
// gate decisions are bit-identical; only the destination (global) changed.
// ---------------------------------------------------------------------------
__global__ __launch_bounds__(256) void router_kernel(
    const float* __restrict__ x,
    const double* __restrict__ wr1d, const double* __restrict__ br1d,
    const double* __restrict__ wr2d, const double* __restrict__ br2d,
    float* __restrict__ gates)
{
    __shared__ __align__(16) char lds[41472];
    float*  xs  = (float*)lds;                 // 64 rows * 130 f32 = 33280 B
    double* rfs = (double*)(lds + 33280);      // 64*16*8 = 8192 B

    const int t    = threadIdx.x;
    const int tok0 = blockIdx.x * 64;

    // stage x fp32 (stride 130 to dodge bank conflicts)
    #pragma unroll
    for (int i = 0; i < 8; ++i) {
        int cid = i * 256 + t;       // 4-float chunk id, 0..2047
        int m = cid >> 5;            // token 0..63
        int c = cid & 31;            // chunk within row
        f32x4 v = *(const f32x4*)(x + (size_t)(tok0 + m) * 128 + c * 4);
        f32x2 s0, s1;
        s0[0] = v[0]; s0[1] = v[1]; s1[0] = v[2]; s1[1] = v[3];
        *(f32x2*)(xs + m * 130 + c * 4)     = s0;
        *(f32x2*)(xs + m * 130 + c * 4 + 2) = s1;
    }
    __syncthreads();

    // ---- router layer 1 (fp64): thread (tok=t&63, rq=(t>>6)*4) -> 4 rf ----
    {
        const int tok = t & 63;
        const int rq  = (t >> 6) * 4;
        const int rqs = __builtin_amdgcn_readfirstlane(rq);  // force s_loads
        double rf4[4];
        #pragma unroll
        for (int j = 0; j < 4; ++j) rf4[j] = br1d[rqs + j];
        const float* xr = xs + tok * 130;
        #pragma unroll 4
        for (int c = 0; c < 64; ++c) {
            f32x2 xv2 = *(const f32x2*)(xr + c * 2);
            #pragma unroll
            for (int q = 0; q < 2; ++q) {
                double xv = (double)xv2[q];
                int k = c * 2 + q;
                #pragma unroll
                for (int j = 0; j < 4; ++j)
                    rf4[j] = fma(xv, wr1d[k * 16 + rqs + j], rf4[j]);
            }
        }
        #pragma unroll
        for (int j = 0; j < 4; ++j)
            rfs[tok * 16 + rq + j] = rf4[j] > 0.0 ? rf4[j] : 0.0;
    }
    __syncthreads();

    // ---- router layer 2 + softmax + div-free mask (fp64), 1 thr/token ----
    if (t < 64) {
        double lg[8];
        #pragma unroll
        for (int j = 0; j < 8; ++j) lg[j] = br2d[j];
        #pragma unroll
        for (int r = 0; r < 16; ++r) {
            double rv = rfs[t * 16 + r];
            #pragma unroll
            for (int j = 0; j < 8; ++j)
                lg[j] = fma(rv, wr2d[r * 8 + j], lg[j]);
        }
        double mx = lg[0];
        #pragma unroll
        for (int j = 1; j < 8; ++j) mx = lg[j] > mx ? lg[j] : mx;
        double ex[8]; double s = 0.0;
        #pragma unroll
        for (int j = 0; j < 8; ++j) { ex[j] = exp(lg[j] - mx); s += ex[j]; }
        double ms = 0.0;
        bool mk[8];
        #pragma unroll
        for (int j = 0; j < 8; ++j) {
            mk[j] = (8.0 * ex[j] > s);
            ms += mk[j] ? ex[j] : 0.0;
        }
        double inv = 1.0 / (ms + s * 1e-8);
        f32x4 o0, o1;
        #pragma unroll
        for (int j = 0; j < 4; ++j) {
            o0[j] = mk[j]     ? (float)(ex[j] * inv)     : 0.f;
            o1[j] = mk[4 + j] ? (float)(ex[4 + j] * inv) : 0.f;
        }
        *(f32x4*)(gates + (size_t)(tok0 + t) * 8)     = o0;
        *(f32x4*)(gates + (size_t)(tok0 + t) * 8 + 4) = o1;
    }
}

// ---------------------------------------------------------------------------
// Fused expert kernel. 64 tokens/block, 4 waves = (token-half mt, out-pair oh).
// Each wave: GEMM1 for n-tiles {2oh,2oh+1} of its token half -> gelu+gate ->
// bf16 H exchange through LDS (layout matched to sigma-permuted w2p) ->
// GEMM2 accumulating the FULL hidden dim for out-tiles {2oh,2oh+1}.
// No cross-wave output reduction; registers ~120 -> 4 waves/SIMD, LDS 34 KB
// -> 4 blocks/CU.
// ---------------------------------------------------------------------------
__global__ __launch_bounds__(256, 4) void moe_main_kernel(
    const float* __restrict__ x, const float* __restrict__ gates,
    const __bf16* __restrict__ w1p, const __bf16* __restrict__ w2p,
    const float* __restrict__ be2, const float* __restrict__ bs2,
    float* __restrict__ out)
{
    __shared__ __align__(16) char lds[34816];
    __bf16* Xp = (__bf16*)lds;                 // 18432 B: [2 mt][9 ks][64][8]
    __bf16* Hs = (__bf16*)(lds + 18432);       // 16384 B: [2 mt][8 kq][64][8]

    const int t    = threadIdx.x;
    const int lane = t & 63;
    const int wave = t >> 6;
    const int l31  = lane & 31;
    const int hi   = lane >> 5;
    const int mt   = wave >> 1;     // token tile (32 tokens)
    const int oh   = wave & 1;      // n-tile pair / out-tile pair selector
    const int tok0 = blockIdx.x * 64;

    // ---- stage X as bf16 B-frags (no fp32 copy needed anymore) ----
    #pragma unroll
    for (int i = 0; i < 4; ++i) {
        int g = i * 256 + t;       // 8-element group id, 0..1023
        int m = g >> 4;            // token 0..63
        int c = g & 15;            // which 8-k chunk
        const f32x4* sp = (const f32x4*)(x + (size_t)(tok0 + m) * 128 + c * 8);
        f32x4 va = sp[0], vb = sp[1];
        bf16x8 v;
        v[0]=(__bf16)va[0]; v[1]=(__bf16)va[1]; v[2]=(__bf16)va[2]; v[3]=(__bf16)va[3];
        v[4]=(__bf16)vb[0]; v[5]=(__bf16)vb[1]; v[6]=(__bf16)vb[2]; v[7]=(__bf16)vb[3];
        *(bf16x8*)&Xp[(((m >> 5) * 9 + (c >> 1)) * 64 + (c & 1) * 32 + (m & 31)) * 8] = v;
    }
    // ks=8 bias column: k=128 -> 1.0, k=129..143 -> 0
    if (t < 128) {
        int mtx = t >> 6, l = t & 63;
        bf16x8 v;
        #pragma unroll
        for (int j = 0; j < 8; ++j) v[j] = (__bf16)0.f;
        if (l < 32) v[0] = (__bf16)1.0f;
        *(bf16x8*)&Xp[((mtx * 9 + 8) * 64 + l) * 8] = v;
    }
    __syncthreads();

    // ---- per-token gates for this wave's token tile ----
    const float* gtp = gates + (size_t)(tok0 + 32 * mt + l31) * 8;
    f32x4 ga4 = *(const f32x4*)gtp;
    f32x4 gb4 = *(const f32x4*)(gtp + 4);
    float gte[8] = {ga4[0], ga4[1], ga4[2], ga4[3], gb4[0], gb4[1], gb4[2], gb4[3]};

    f32x16 acc0, acc1;
    #pragma unroll
    for (int i = 0; i < 16; ++i) { acc0[i] = 0.f; acc1[i] = 0.f; }

    const bf16x8* w1v = (const bf16x8*)w1p;
    const bf16x8* w2v = (const bf16x8*)w2p;

    #pragma unroll 1
    for (int e = 0; e < 10; ++e) {
        const float gv = (e < 8) ? gte[e] : 1.0f;

        // ---- GEMM1 + gelu + gate -> Hs, for n-tiles 2oh, 2oh+1 ----
        #pragma unroll
        for (int nti = 0; nti < 2; ++nti) {
            const int nt = 2 * oh + nti;
            const bf16x8* wp = w1v + ((size_t)(e * 4 + nt) * 9) * 64 + lane;
            bf16x8 wb[9];
            #pragma unroll
            for (int ks = 0; ks < 9; ++ks) wb[ks] = wp[ks * 64];
            f32x16 a1;
            #pragma unroll
            for (int i = 0; i < 16; ++i) a1[i] = 0.f;
            #pragma unroll
            for (int ks = 0; ks < 9; ++ks) {
                bf16x8 xb = *(const bf16x8*)&Xp[((mt * 9 + ks) * 64 + lane) * 8];
                a1 = mfma32(wb[ks], xb, a1);
            }
            // gelu+gate: a1 reg 4*g4+q holds hidden h = 32nt + 8*g4 + 4*hi + q
            // -> write 4 bf16 at Hs[mt][2nt + (g4>>1)][lane], byte off 8*(g4&1)
            // which matches w2p's permuted k = 16kq + 8(j>>2) + 4hi + (j&3).
            #pragma unroll
            for (int g4 = 0; g4 < 4; ++g4) {
                bf16x4 pk;
                #pragma unroll
                for (int qp = 0; qp < 2; ++qp) {
                    float h0 = a1[4 * g4 + 2 * qp];
                    float h1 = a1[4 * g4 + 2 * qp + 1];
                    float t0 = h0 * h0, t1 = h1 * h1;
                    float p0 = fmaf(t0, -GELU_C2, -GELU_C1);
                    float p1 = fmaf(t1, -GELU_C2, -GELU_C1);
                    float m0 = h0 * p0, m1 = h1 * p1;
                    float e0 = __builtin_amdgcn_exp2f(m0);
                    float e1 = __builtin_amdgcn_exp2f(m1);
                    float q0 = __builtin_amdgcn_rcpf(1.f + e0);
                    float q1 = __builtin_amdgcn_rcpf(1.f + e1);
                    pk[2 * qp]     = (__bf16)(h0 * q0 * gv);
                    pk[2 * qp + 1] = (__bf16)(h1 * q1 * gv);
                }
                *(bf16x4*)&Hs[((mt * 8 + 2 * nt + (g4 >> 1)) * 64 + lane) * 8
                              + 4 * (g4 & 1)] = pk;
            }
        }
        __syncthreads();

        // ---- GEMM2: full hidden (kq 0..7) for out-tiles 2oh, 2oh+1 ----
        {
            const bf16x8* wBp = w2v + ((size_t)e * 32 + (2 * oh) * 8) * 64 + lane;
            #pragma unroll
            for (int kq = 0; kq < 8; ++kq) {
                bf16x8 hf = *(const bf16x8*)&Hs[((mt * 8 + kq) * 64 + lane) * 8];
                bf16x8 wB0 = wBp[kq * 64];
                bf16x8 wB1 = wBp[(8 + kq) * 64];
                acc0 = mfma32(hf, wB0, acc0);
                acc1 = mfma32(hf, wB1, acc1);
            }
        }
        __syncthreads();
    }

    // ---- epilogue: bias (gate-weighted be2 + summed bs2) + store ----
    {
        float be2c[2][8], bsc[2];
        #pragma unroll
        for (int oti = 0; oti < 2; ++oti) {
            int o = 32 * (2 * oh + oti) + l31;
            bsc[oti] = bs2[o] + bs2[128 + o];
            #pragma unroll
            for (int ee = 0; ee < 8; ++ee) be2c[oti][ee] = be2[ee * 128 + o];
        }
        const float* mgb = gates + (size_t)(tok0 + 32 * mt) * 8;
        #pragma unroll
        for (int r = 0; r < 16; ++r) {
            int mrow = (r & 3) + 8 * (r >> 2) + 4 * hi;
            f32x4 g0 = *(const f32x4*)&mgb[mrow * 8];
            f32x4 g1 = *(const f32x4*)&mgb[mrow * 8 + 4];
            size_t orow = (size_t)(tok0 + 32 * mt + mrow) * 128;
            float b0 = bsc[0], b1 = bsc[1];
            #pragma unroll
            for (int ee = 0; ee < 4; ++ee) {
                b0 = fmaf(g0[ee], be2c[0][ee], b0);
                b1 = fmaf(g0[ee], be2c[1][ee], b1);
            }
            #pragma unroll
            for (int ee = 0; ee < 4; ++ee) {
                b0 = fmaf(g1[ee], be2c[0][4 + ee], b0);
                b1 = fmaf(g1[ee], be2c[1][4 + ee], b1);
            }
            out[orow + 32 * (2 * oh)     + l31] = acc0[r] + b0;
            out[orow + 32 * (2 * oh + 1) + l31] = acc1[r] + b1;
        }
    }
}

// ---------------------------------------------------------------------------
extern "C" void kernel_launch(void* const* d_in, const int* in_sizes, int n_in,
                              void* d_out, int out_size, void* d_ws, size_t ws_size,
                              hipStream_t stream)
{
    const float* x   = (const float*)d_in[0];
    const float* Wr1 = (const float*)d_in[1];
    const float* br1 = (const float*)d_in[2];
    const float* Wr2 = (const float*)d_in[3];
    const float* br2 = (const float*)d_in[4];
    const float* We1 = (const float*)d_in[5];
    const float* be1 = (const float*)d_in[6];
    const float* We2 = (const float*)d_in[7];
    const float* be2 = (const float*)d_in[8];
    const float* Ws1 = (const float*)d_in[9];
    const float* bs1 = (const float*)d_in[10];
    const float* Ws2 = (const float*)d_in[11];
    const float* bs2 = (const float*)d_in[12];

    // ws: [0,368640) W1p bf16; [368640,696320) W2p bf16; fp64 router weights;
    // [720896, 720896+2097152) gates f32 [65536][8]
    __bf16* w1p  = (__bf16*)d_ws;
    __bf16* w2p  = (__bf16*)((char*)d_ws + 368640);
    double* wr1d = (double*)((char*)d_ws + 696320);
    double* wr2d = (double*)((char*)d_ws + 712704);
    double* br1d = (double*)((char*)d_ws + 713728);
    double* br2d = (double*)((char*)d_ws + 713856);
    float*  gts  = (float*)((char*)d_ws + 720896);

    pack_kernel<<<179, 256, 0, stream>>>(We1, be1, Ws1, bs1, We2, Ws2,
                                         Wr1, br1, Wr2, br2,
                                         w1p, w2p, wr1d, br1d, wr2d, br2d);
    router_kernel<<<1024, 256, 0, stream>>>(x, wr1d, br1d, wr2d, br2d, gts);
    moe_main_kernel<<<1024, 256, 0, stream>>>(x, gts, w1p, w2p, be2, bs2,
                                              (float*)d_out);
}

// Round 2
// 184.529 us; speedup vs baseline: 1.0013x; 1.0013x over previous
//
#include <hip/hip_runtime.h>
#include <hip/hip_bf16.h>

typedef __bf16 bf16x8 __attribute__((ext_vector_type(8)));
typedef __bf16 bf16x4 __attribute__((ext_vector_type(4)));
typedef float  f32x16 __attribute__((ext_vector_type(16)));
typedef float  f32x4  __attribute__((ext_vector_type(4)));
typedef float  f32x2  __attribute__((ext_vector_type(2)));

static __device__ __forceinline__ f32x16 mfma32(bf16x8 a, bf16x8 b, f32x16 c) {
    return __builtin_amdgcn_mfma_f32_32x32x16_bf16(a, b, c, 0, 0, 0);
}

// gelu-tanh via sigmoid with log2e folded in:
// gelu(h) = h / (1 + exp2(-h*(C1 + C2*h^2)))
#define GELU_C1 2.30220820f
#define GELU_C2 0.10294324f

// gelu+gate on 8 consecutive elements of an accumulator (base = 0 or 8)
static __device__ __forceinline__ bf16x8 gelu8(f32x16 a, int base, float gv) {
    bf16x8 r;
    #pragma unroll
    for (int p = 0; p < 4; ++p) {
        f32x2 hh; hh[0] = a[base + 2 * p]; hh[1] = a[base + 2 * p + 1];
        f32x2 tt = hh * hh;
        f32x2 pp;
        pp[0] = fmaf(tt[0], -GELU_C2, -GELU_C1);
        pp[1] = fmaf(tt[1], -GELU_C2, -GELU_C1);
        f32x2 mm = hh * pp;
        float e0 = __builtin_amdgcn_exp2f(mm[0]);
        float e1 = __builtin_amdgcn_exp2f(mm[1]);
        float q0 = __builtin_amdgcn_rcpf(1.f + e0);
        float q1 = __builtin_amdgcn_rcpf(1.f + e1);
        r[2 * p]     = (__bf16)(hh[0] * q0 * gv);
        r[2 * p + 1] = (__bf16)(hh[1] * q1 * gv);
    }
    return r;
}

// ---------------------------------------------------------------------------
// Pack kernel: W1p (K=144, bias folded), W2p (sigma-permuted), plus router
// weights converted to fp64. Unchanged.
// ---------------------------------------------------------------------------
__global__ __launch_bounds__(256) void pack_kernel(
    const float* __restrict__ We1, const float* __restrict__ be1,
    const float* __restrict__ Ws1, const float* __restrict__ bs1,
    const float* __restrict__ We2, const float* __restrict__ Ws2,
    const float* __restrict__ Wr1, const float* __restrict__ br1,
    const float* __restrict__ Wr2, const float* __restrict__ br2,
    __bf16* __restrict__ w1p, __bf16* __restrict__ w2p,
    double* __restrict__ wr1d, double* __restrict__ br1d,
    double* __restrict__ wr2d, double* __restrict__ br2d)
{
    int tid = blockIdx.x * 256 + threadIdx.x;
    if (tid < 23040) {
        int l  = tid & 63;
        int ks = (tid >> 6) % 9;
        int nt = (tid / 576) & 3;
        int e  = tid / 2304;
        const float* src = (e < 8) ? (We1 + e * 16384) : (Ws1 + (e - 8) * 16384);
        const float* bia = (e < 8) ? (be1 + e * 128)   : (bs1 + (e - 8) * 128);
        int n = nt * 32 + (l & 31);
        int kb = ks * 16 + (l >> 5) * 8;
        bf16x8 v;
        #pragma unroll
        for (int j = 0; j < 8; ++j) {
            int k = kb + j;
            float f = (k < 128) ? src[k * 128 + n] : ((k == 128) ? bia[n] : 0.f);
            v[j] = (__bf16)f;
        }
        *(bf16x8*)(w1p + (size_t)tid * 8) = v;
    } else if (tid < 43520) {
        int t2 = tid - 23040;
        int l  = t2 & 63;
        int ks = (t2 >> 6) & 7;
        int ot = (t2 / 512) & 3;
        int e  = t2 / 2048;
        const float* src = (e < 8) ? (We2 + e * 16384) : (Ws2 + (e - 8) * 16384);
        int o  = ot * 32 + (l & 31);
        int lh = l >> 5;
        bf16x8 v;
        #pragma unroll
        for (int j = 0; j < 8; ++j) {
            int hid = 16 * ks + 8 * (j >> 2) + 4 * lh + (j & 3);
            v[j] = (__bf16)src[hid * 128 + o];
        }
        *(bf16x8*)(w2p + (size_t)t2 * 8) = v;
    } else if (tid < 45568) {
        int i = tid - 43520;            // 0..2047: Wr1 [128][16]
        wr1d[i] = (double)Wr1[i];
    } else if (tid < 45696) {
        int i = tid - 45568;            // 0..127: Wr2 [16][8]
        wr2d[i] = (double)Wr2[i];
    } else if (tid < 45712) {
        int i = tid - 45696;            // 0..15
        br1d[i] = (double)br1[i];
    } else if (tid < 45720) {
        int i = tid - 45712;            // 0..7
        br2d[i] = (double)br2[i];
    }
}

// ---------------------------------------------------------------------------
// Router kernel (fp64, decision-exact). Same fp64 arithmetic as before
// (layer1 / layer2 fma order and exp identical -> bit-identical decisions),
// but the layer-2 + exp tail is parallelized across all 256 threads
// (was: 64 threads x 8 serial fp64 exp), and LDS rows are padded to kill
// the 32-way stride-128B bank conflicts on rfs.
// ---------------------------------------------------------------------------
__global__ __launch_bounds__(256) void router_kernel(
    const float* __restrict__ x,
    const double* __restrict__ wr1d, const double* __restrict__ br1d,
    const double* __restrict__ wr2d, const double* __restrict__ br2d,
    float* __restrict__ gates)
{
    __shared__ __align__(16) char lds[51200];
    float*  xs  = (float*)lds;                  // 64*130*4 = 33280 B
    double* rfs = (double*)(lds + 33280);       // 64*17*8  =  8704 B (pad 17)
    double* lgs = (double*)(lds + 41984);       // 64*9*8   =  4608 B (pad 9)
    double* exs = (double*)(lds + 46592);       // 64*9*8   =  4608 B (pad 9)

    const int t    = threadIdx.x;
    const int tok0 = blockIdx.x * 64;

    // stage x fp32 (stride 130)
    #pragma unroll
    for (int i = 0; i < 8; ++i) {
        int cid = i * 256 + t;
        int m = cid >> 5;
        int c = cid & 31;
        f32x4 v = *(const f32x4*)(x + (size_t)(tok0 + m) * 128 + c * 4);
        f32x2 s0, s1;
        s0[0] = v[0]; s0[1] = v[1]; s1[0] = v[2]; s1[1] = v[3];
        *(f32x2*)(xs + m * 130 + c * 4)     = s0;
        *(f32x2*)(xs + m * 130 + c * 4 + 2) = s1;
    }
    __syncthreads();

    // ---- layer 1 (fp64): thread (tok=t&63, rq=(t>>6)*4) -> 4 rf ----
    {
        const int tok = t & 63;
        const int rq  = (t >> 6) * 4;
        const int rqs = __builtin_amdgcn_readfirstlane(rq);
        double rf4[4];
        #pragma unroll
        for (int j = 0; j < 4; ++j) rf4[j] = br1d[rqs + j];
        const float* xr = xs + tok * 130;
        #pragma unroll 4
        for (int c = 0; c < 64; ++c) {
            f32x2 xv2 = *(const f32x2*)(xr + c * 2);
            #pragma unroll
            for (int q = 0; q < 2; ++q) {
                double xv = (double)xv2[q];
                int k = c * 2 + q;
                #pragma unroll
                for (int j = 0; j < 4; ++j)
                    rf4[j] = fma(xv, wr1d[k * 16 + rqs + j], rf4[j]);
            }
        }
        #pragma unroll
        for (int j = 0; j < 4; ++j)
            rfs[tok * 17 + rqs + j] = rf4[j] > 0.0 ? rf4[j] : 0.0;
    }
    __syncthreads();

    // ---- layer 2: thread (tok, jq=t>>6) computes 2 logits ----
    const int tok = t & 63;
    const int j0  = __builtin_amdgcn_readfirstlane((t >> 6) * 2);
    double lgA = br2d[j0], lgB = br2d[j0 + 1];
    #pragma unroll
    for (int r = 0; r < 16; ++r) {
        double rv = rfs[tok * 17 + r];
        lgA = fma(rv, wr2d[r * 8 + j0],     lgA);
        lgB = fma(rv, wr2d[r * 8 + j0 + 1], lgB);
    }
    lgs[tok * 9 + j0]     = lgA;
    lgs[tok * 9 + j0 + 1] = lgB;
    __syncthreads();

    // ---- exp: each thread does 2 fp64 exps (max recomputed redundantly) ----
    {
        double mx = lgs[tok * 9];
        #pragma unroll
        for (int k = 1; k < 8; ++k) {
            double v = lgs[tok * 9 + k];
            mx = v > mx ? v : mx;
        }
        exs[tok * 9 + j0]     = exp(lgA - mx);
        exs[tok * 9 + j0 + 1] = exp(lgB - mx);
    }
    __syncthreads();

    // ---- decision + gates (1 thr/token) ----
    if (t < 64) {
        double ex[8]; double s = 0.0;
        #pragma unroll
        for (int j = 0; j < 8; ++j) { ex[j] = exs[t * 9 + j]; s += ex[j]; }
        double ms = 0.0;
        bool mk[8];
        #pragma unroll
        for (int j = 0; j < 8; ++j) {
            mk[j] = (8.0 * ex[j] > s);
            ms += mk[j] ? ex[j] : 0.0;
        }
        double inv = 1.0 / (ms + s * 1e-8);
        f32x4 o0, o1;
        #pragma unroll
        for (int j = 0; j < 4; ++j) {
            o0[j] = mk[j]     ? (float)(ex[j] * inv)     : 0.f;
            o1[j] = mk[4 + j] ? (float)(ex[4 + j] * inv) : 0.f;
        }
        *(f32x4*)(gates + (size_t)(tok0 + t) * 8)     = o0;
        *(f32x4*)(gates + (size_t)(tok0 + t) * 8 + 4) = o1;
    }
}

// ---------------------------------------------------------------------------
// Fused expert kernel v2. 128 tokens/block, 4 waves = (mp, oh); each wave
// owns TWO token tiles (mt = 2mp, 2mp+1), n-tiles {2oh,2oh+1} for GEMM1 and
// out-tiles {2oh,2oh+1} for GEMM2 -> every W1/W2 fragment feeds 2x the MFMAs
// (halves per-expert weight L2 traffic vs v1). W2 ot=2oh prefetched before
// GEMM1 (drains at barrier = hidden); ot=2oh+1 issued at GEMM2 top.
// Bias column of X synthesized in registers (Xp has 8 ks only).
// LDS 68 KB -> 2 blocks/CU; regs ~230 -> 2 waves/SIMD.
// ---------------------------------------------------------------------------
__global__ __launch_bounds__(256, 2) void moe_main_kernel(
    const float* __restrict__ x, const float* __restrict__ gates,
    const __bf16* __restrict__ w1p, const __bf16* __restrict__ w2p,
    const float* __restrict__ be2, const float* __restrict__ bs2,
    float* __restrict__ out)
{
    __shared__ __align__(16) char lds[69632];
    __bf16* Xp = (__bf16*)lds;               // [4 mt][8 ks][64][8] = 32768 B
    __bf16* Hs = (__bf16*)(lds + 32768);     // [4 mt][8 kq][64][8] = 32768 B
    float*  mg = (float*)(lds + 65536);      // [128][8] = 4096 B

    const int t    = threadIdx.x;
    const int lane = t & 63;
    const int wave = t >> 6;
    const int l31  = lane & 31;
    const int hi   = lane >> 5;
    const int mp   = wave >> 1;
    const int oh   = wave & 1;
    const int tok0 = blockIdx.x * 128;

    // ---- stage X as bf16 B-frags (ks 0..7 real data only) ----
    #pragma unroll
    for (int i = 0; i < 8; ++i) {
        int g = i * 256 + t;       // 8-elem group id, 0..2047
        int m = g >> 4;            // token 0..127
        int c = g & 15;            // 8-k chunk
        const f32x4* sp = (const f32x4*)(x + (size_t)(tok0 + m) * 128 + c * 8);
        f32x4 va = sp[0], vb = sp[1];
        bf16x8 v;
        v[0]=(__bf16)va[0]; v[1]=(__bf16)va[1]; v[2]=(__bf16)va[2]; v[3]=(__bf16)va[3];
        v[4]=(__bf16)vb[0]; v[5]=(__bf16)vb[1]; v[6]=(__bf16)vb[2]; v[7]=(__bf16)vb[3];
        *(bf16x8*)&Xp[(((m >> 5) * 8 + (c >> 1)) * 64 + (c & 1) * 32 + (m & 31)) * 8] = v;
    }
    // ---- stage gates [128][8] into LDS ----
    {
        int m = t >> 1, half = t & 1;
        f32x4 g = *(const f32x4*)(gates + (size_t)(tok0 + m) * 8 + half * 4);
        *(f32x4*)&mg[m * 8 + half * 4] = g;
    }
    __syncthreads();

    // bias-column frag (k=128 -> 1.0) kept in registers
    bf16x8 xbias;
    #pragma unroll
    for (int j = 0; j < 8; ++j) xbias[j] = (__bf16)0.f;
    if (lane < 32) xbias[0] = (__bf16)1.0f;

    f32x16 acc00, acc01, acc10, acc11;
    #pragma unroll
    for (int i = 0; i < 16; ++i) { acc00[i]=0.f; acc01[i]=0.f; acc10[i]=0.f; acc11[i]=0.f; }

    const bf16x8* w1v = (const bf16x8*)w1p;
    const bf16x8* w2v = (const bf16x8*)w2p;

    #pragma unroll 1
    for (int e = 0; e < 10; ++e) {
        const bf16x8* wp  = w1v + ((size_t)(e * 4 + 2 * oh) * 9) * 64 + lane;
        const bf16x8* wBp = w2v + ((size_t)(e * 4 + 2 * oh) * 8) * 64 + lane;
        // W1 frags for both n-tiles (each used by 2 mt tiles)
        bf16x8 wb0[9], wb1[9];
        #pragma unroll
        for (int ks = 0; ks < 9; ++ks) wb0[ks] = wp[ks * 64];
        #pragma unroll
        for (int ks = 0; ks < 9; ++ks) wb1[ks] = wp[(9 + ks) * 64];
        // prefetch W2 ot=2oh (drains at the barrier -> latency hidden)
        bf16x8 wB0[8];
        #pragma unroll
        for (int kq = 0; kq < 8; ++kq) wB0[kq] = wBp[kq * 64];

        // ---- GEMM1 + gelu + gate -> Hs, for both mt tiles ----
        #pragma unroll
        for (int mi = 0; mi < 2; ++mi) {
            const int mt = 2 * mp + mi;
            float gv = 1.0f;
            if (e < 8) gv = mg[(32 * mt + l31) * 8 + e];
            f32x16 a0, a1;
            #pragma unroll
            for (int i = 0; i < 16; ++i) { a0[i] = 0.f; a1[i] = 0.f; }
            #pragma unroll
            for (int ks = 0; ks < 8; ++ks) {
                bf16x8 xb = *(const bf16x8*)&Xp[((mt * 8 + ks) * 64 + lane) * 8];
                a0 = mfma32(wb0[ks], xb, a0);
                a1 = mfma32(wb1[ks], xb, a1);
            }
            a0 = mfma32(wb0[8], xbias, a0);
            a1 = mfma32(wb1[8], xbias, a1);
            // rows 4oh..4oh+3 of this mt, b128 writes
            int rb = (mt * 8 + 4 * oh) * 64 + lane;
            *(bf16x8*)&Hs[(rb + 0 * 64) * 8] = gelu8(a0, 0, gv);
            *(bf16x8*)&Hs[(rb + 1 * 64) * 8] = gelu8(a0, 8, gv);
            *(bf16x8*)&Hs[(rb + 2 * 64) * 8] = gelu8(a1, 0, gv);
            *(bf16x8*)&Hs[(rb + 3 * 64) * 8] = gelu8(a1, 8, gv);
        }
        __syncthreads();

        // W2 ot=2oh+1 issued at phase top (hides under first-ot MFMAs)
        bf16x8 wB1[8];
        #pragma unroll
        for (int kq = 0; kq < 8; ++kq) wB1[kq] = wBp[(8 + kq) * 64];

        // ---- GEMM2: full hidden, 2 mt x 2 ot, 4 independent acc chains ----
        __builtin_amdgcn_s_setprio(1);
        #pragma unroll
        for (int kq = 0; kq < 8; ++kq) {
            bf16x8 h0 = *(const bf16x8*)&Hs[(((2 * mp)     * 8 + kq) * 64 + lane) * 8];
            bf16x8 h1 = *(const bf16x8*)&Hs[(((2 * mp + 1) * 8 + kq) * 64 + lane) * 8];
            acc00 = mfma32(h0, wB0[kq], acc00);
            acc01 = mfma32(h0, wB1[kq], acc01);
            acc10 = mfma32(h1, wB0[kq], acc10);
            acc11 = mfma32(h1, wB1[kq], acc11);
        }
        __builtin_amdgcn_s_setprio(0);
        __syncthreads();
    }

    // ---- epilogue: bias (gate-weighted be2 + summed bs2) + store ----
    {
        float be2c[2][8], bsc[2];
        #pragma unroll
        for (int oti = 0; oti < 2; ++oti) {
            int o = 32 * (2 * oh + oti) + l31;
            bsc[oti] = bs2[o] + bs2[128 + o];
            #pragma unroll
            for (int ee = 0; ee < 8; ++ee) be2c[oti][ee] = be2[ee * 128 + o];
        }
        #pragma unroll
        for (int mi = 0; mi < 2; ++mi) {
            const int mt = 2 * mp + mi;
            const float* mgb = mg + (32 * mt) * 8;
            f32x16 aA = mi ? acc10 : acc00;
            f32x16 aB = mi ? acc11 : acc01;
            #pragma unroll
            for (int r = 0; r < 16; ++r) {
                int mrow = (r & 3) + 8 * (r >> 2) + 4 * hi;
                f32x4 g0 = *(const f32x4*)&mgb[mrow * 8];
                f32x4 g1 = *(const f32x4*)&mgb[mrow * 8 + 4];
                size_t orow = (size_t)(tok0 + 32 * mt + mrow) * 128;
                float b0 = bsc[0], b1 = bsc[1];
                #pragma unroll
                for (int ee = 0; ee < 4; ++ee) {
                    b0 = fmaf(g0[ee], be2c[0][ee], b0);
                    b1 = fmaf(g0[ee], be2c[1][ee], b1);
                }
                #pragma unroll
                for (int ee = 0; ee < 4; ++ee) {
                    b0 = fmaf(g1[ee], be2c[0][4 + ee], b0);
                    b1 = fmaf(g1[ee], be2c[1][4 + ee], b1);
                }
                out[orow + 32 * (2 * oh)     + l31] = aA[r] + b0;
                out[orow + 32 * (2 * oh + 1) + l31] = aB[r] + b1;
            }
        }
    }
}

// ---------------------------------------------------------------------------
extern "C" void kernel_launch(void* const* d_in, const int* in_sizes, int n_in,
                              void* d_out, int out_size, void* d_ws, size_t ws_size,
                              hipStream_t stream)
{
    const float* x   = (const float*)d_in[0];
    const float* Wr1 = (const float*)d_in[1];
    const float* br1 = (const float*)d_in[2];
    const float* Wr2 = (const float*)d_in[3];
    const float* br2 = (const float*)d_in[4];
    const float* We1 = (const float*)d_in[5];
    const float* be1 = (const float*)d_in[6];
    const float* We2 = (const float*)d_in[7];
    const float* be2 = (const float*)d_in[8];
    const float* Ws1 = (const float*)d_in[9];
    const float* bs1 = (const float*)d_in[10];
    const float* Ws2 = (const float*)d_in[11];
    const float* bs2 = (const float*)d_in[12];

    // ws: [0,368640) W1p bf16; [368640,696320) W2p bf16; fp64 router weights;
    // [720896, 720896+2097152) gates f32 [65536][8]
    __bf16* w1p  = (__bf16*)d_ws;
    __bf16* w2p  = (__bf16*)((char*)d_ws + 368640);
    double* wr1d = (double*)((char*)d_ws + 696320);
    double* wr2d = (double*)((char*)d_ws + 712704);
    double* br1d = (double*)((char*)d_ws + 713728);
    double* br2d = (double*)((char*)d_ws + 713856);
    float*  gts  = (float*)((char*)d_ws + 720896);

    pack_kernel<<<179, 256, 0, stream>>>(We1, be1, Ws1, bs1, We2, Ws2,
                                         Wr1, br1, Wr2, br2,
                                         w1p, w2p, wr1d, br1d, wr2d, br2d);
    router_kernel<<<1024, 256, 0, stream>>>(x, wr1d, br1d, wr2d, br2d, gts);
    moe_main_kernel<<<512, 256, 0, stream>>>(x, gts, w1p, w2p, be2, bs2,
                                             (float*)d_out);
}